// Round 9
// baseline (131.911 us; speedup 1.0000x reference)
//
#include <hip/hip_runtime.h>
#include <math.h>

#define SR      44100.0
#define T_LEN   441000
#define B_ROWS  32
#define NCH     13782            // chunks per row (32 samples each; last = 8)
#define BPR     54               // blocks per row (256 chunks per block)
#define NBLK    (B_ROWS * BPR)   // 1728
#define NMAT    9                // W^(2^k), k=0..8  (W = A^32; W^256 = sVm[8])

// ws layout: [0] ticket (int) | float idx 16: flags[1728] (uint) |
//            float idx 2048: AG[1728][6] | float idx 12416: INC[1728][6]
#define WS_AG   2048
#define WS_INC  12416

typedef __attribute__((address_space(1))) const void gconst_t;
typedef __attribute__((address_space(3))) void lds_t;
#define GL2LDS(gp, lp) __builtin_amdgcn_global_load_lds((gconst_t*)(gp), (lds_t*)(lp), 16, 0, 0)

#define AGENT __HIP_MEMORY_SCOPE_AGENT

// ---------------- shared helpers (verified in rounds 3..8) ----------------

#define COMPUTE_COEFS(scoef, dco, qs, gains) do { \
    if (threadIdx.x < 3) { \
      int f = threadIdx.x; \
      double cfq = 100.0 * exp(log(30.0) * (double)f / 3.0); \
      double w0 = 2.0 * M_PI * cfq / SR; \
      double alpha = sin(w0) / (2.0 * (double)qs[f]); \
      double Ag = exp((double)gains[f] * (2.302585092994045684 / 40.0)); \
      double a0 = 1.0 + alpha / Ag; \
      double c0 = (1.0 + alpha * Ag) / a0; \
      double c1 = (-2.0 * cos(w0)) / a0; \
      double c2 = (1.0 - alpha * Ag) / a0; \
      double c3 = c1; \
      double c4 = (1.0 - alpha / Ag) / a0; \
      dco[f*5+0]=c0; dco[f*5+1]=c1; dco[f*5+2]=c2; dco[f*5+3]=c3; dco[f*5+4]=c4; \
      scoef[f*5+0]=(float)c0; scoef[f*5+1]=(float)c1; scoef[f*5+2]=(float)c2; \
      scoef[f*5+3]=(float)c3; scoef[f*5+4]=(float)c4; \
    } \
  } while (0)

#define LOAD_COEFS(cf) \
  const float b00=cf[0],b10=cf[1],b20=cf[2],a10=cf[3],a20=cf[4]; \
  const float b01=cf[5],b11=cf[6],b21=cf[7],a11=cf[8],a21=cf[9]; \
  const float b02=cf[10],b12=cf[11],b22=cf[12],a12=cf[13],a22=cf[14];

#define CASCADE_STEP(xx) do { \
    float y1 = fmaf(b00, (xx), s11); \
    s11 = fmaf(-a10, y1, fmaf(b10, (xx), s21)); \
    s21 = fmaf(-a20, y1, b20 * (xx)); \
    float y2 = fmaf(b01, y1, s12); \
    s12 = fmaf(-a11, y2, fmaf(b11, y1, s22)); \
    s22 = fmaf(-a21, y2, b21 * y1); \
    y3 = fmaf(b02, y2, s13); \
    s13 = fmaf(-a12, y3, fmaf(b12, y2, s23)); \
    s23 = fmaf(-a22, y3, b22 * y2); \
  } while (0)

#define MV6(dst, M, v, add) do { \
    _Pragma("unroll") \
    for (int _i = 0; _i < 6; _i++) { \
      float _s = (add)[_i]; \
      _Pragma("unroll") \
      for (int _k = 0; _k < 6; _k++) _s = fmaf((M)[_i*6+_k], (v)[_k], _s); \
      (dst)[_i] = _s; \
    } \
  } while (0)

__device__ __forceinline__ void mm6d(const double* X, const double* Y, double* Z, int t) {
  if (t < 36) {
    int i = t / 6, j = t % 6;
    double s = 0.0;
    #pragma unroll
    for (int k = 0; k < 6; k++) s += X[i*6+k] * Y[k*6+j];
    Z[t] = s;
  }
}

// Staging swizzle: LDS float4-slot s holds global float4 g(s)=(s&~7)|((s&7)^((s>>3)&7)).
// Involution, line-local (coalescing intact), ds_read_b128 bank-balanced.

__global__ __launch_bounds__(256) void fused(const float* __restrict__ x,
                                             const float* __restrict__ qs,
                                             const float* __restrict__ gains,
                                             float* __restrict__ y,
                                             float* __restrict__ ws) {
  __shared__ __align__(16) float lds[4 * 2048];   // 4 waves x 8KB audio slabs (kept live)
  __shared__ double Da[36], Db[36], dco[15];
  __shared__ float sVm[NMAT][36];
  __shared__ float scoef[16];
  __shared__ float wtot[4][6];
  __shared__ float sO[6];
  __shared__ float gstack[54][6];
  __shared__ int sTick;
  const int tid = threadIdx.x;
  const int wib = tid >> 6, lane = tid & 63;

  unsigned int* flags = (unsigned int*)ws + 16;
  float* AGp  = ws + WS_AG;
  float* INCp = ws + WS_INC;

  // ---- ticket: work id decoupled from HW dispatch order (forward-progress safe) ----
  if (tid == 0)
    sTick = __hip_atomic_fetch_add((int*)ws, 1, __ATOMIC_RELAXED, AGENT);
  __syncthreads();
  const int vbid = sTick;
  const int row = vbid / BPR, jb = vbid - row * BPR;

  // ---- stage audio (once): wave wib covers block-chunks wib*64..+63 ----
  const int wci = (jb << 2) + wib;
  long rowbase = (long)row * T_LEN;
  int s0 = wci << 11;
  int span4 = (min(2048, T_LEN - s0)) >> 2;        // 512, or 170 for last wave of row
  const float4* xp = (const float4*)(x + rowbase + s0);
  float* slab = lds + (wib << 11);
  if (span4 == 512) {
    #pragma unroll
    for (int i = 0; i < 8; i++) {
      int s = (i << 6) + lane;
      int g = (s & ~7) | ((s & 7) ^ ((s >> 3) & 7));
      GL2LDS(xp + g, slab + (i << 8));
    }
  } else {
    #pragma unroll
    for (int i = 0; i < 8; i++) {
      int s = (i << 6) + lane;
      int g = (s & ~7) | ((s & 7) ^ ((s >> 3) & 7));
      if (g < span4) GL2LDS(xp + g, slab + (i << 8));
    }
  }
  COMPUTE_COEFS(scoef, dco, qs, gains);
  // wave 0: matrix chain in double (DS ops in-order within a wave; no block barriers)
  if (wib == 0) {
    if (lane == 0) {
      double u[7] = {0,0,0,0,0,0,1};   // current filter input as linear form over (S, x)
      for (int f = 0; f < 3; f++) {
        double c0=dco[f*5+0], c1=dco[f*5+1], c2=dco[f*5+2], c3=dco[f*5+3], c4=dco[f*5+4];
        double yv[7], s1p[7], s2p[7];
        for (int i = 0; i < 7; i++) {
          yv[i]  = c0 * u[i] + ((i == 2*f)   ? 1.0 : 0.0);
          s1p[i] = c1 * u[i] + ((i == 2*f+1) ? 1.0 : 0.0) - c3 * yv[i];
          s2p[i] = c2 * u[i] - c4 * yv[i];
        }
        for (int i = 0; i < 6; i++) { Da[(2*f)*6+i] = s1p[i]; Da[(2*f+1)*6+i] = s2p[i]; }
        for (int i = 0; i < 7; i++) u[i] = yv[i];
      }
    }
    double* cur = Da; double* oth = Db;
    #pragma unroll
    for (int s = 0; s < 5; s++) {                  // A -> A^32 = W
      mm6d(cur, cur, oth, lane);
      double* tm = cur; cur = oth; oth = tm;
    }
    #pragma unroll
    for (int k = 0; k < NMAT; k++) {               // sVm[k] = W^(2^k)
      if (lane < 36) sVm[k][lane] = (float)cur[lane];
      if (k < NMAT - 1) {
        mm6d(cur, cur, oth, lane);
        double* tm = cur; cur = oth; oth = tm;
      }
    }
  }
  __syncthreads();

  // ---- chunk finals from zero entry ----
  int ci = (jb << 8) + tid;                        // chunk index within row
  bool valid = ci < NCH;
  float f6[6] = {0,0,0,0,0,0};
  {
    LOAD_COEFS(scoef);
    if (valid) {
      int n4 = (ci == NCH - 1) ? 2 : 8;
      const float* rowp = slab + (lane << 5);
      int xr = lane & 7;
      float s11=0,s21=0,s12=0,s22=0,s13=0,s23=0, y3;
      if (n4 == 8) {
        #pragma unroll
        for (int j4 = 0; j4 < 8; j4++) {
          float4 v = *(const float4*)(rowp + ((j4 ^ xr) << 2));
          CASCADE_STEP(v.x); CASCADE_STEP(v.y); CASCADE_STEP(v.z); CASCADE_STEP(v.w);
        }
      } else {
        for (int j4 = 0; j4 < 2; j4++) {
          float4 v = *(const float4*)(rowp + ((j4 ^ xr) << 2));
          CASCADE_STEP(v.x); CASCADE_STEP(v.y); CASCADE_STEP(v.z); CASCADE_STEP(v.w);
        }
      }
      (void)y3;
      f6[0]=s11; f6[1]=s21; f6[2]=s12; f6[3]=s22; f6[4]=s13; f6[5]=s23;
    }
  }

  // ---- wave-level shuffle scan (audio slabs untouched) ----
  float v6[6];
  #pragma unroll
  for (int i = 0; i < 6; i++) v6[i] = f6[i];
  #pragma unroll
  for (int k = 0; k < 6; k++) {
    int d = 1 << k;
    float u[6];
    #pragma unroll
    for (int i = 0; i < 6; i++) u[i] = __shfl_up(v6[i], d, 64);
    float nv[6];
    MV6(nv, sVm[k], u, v6);
    #pragma unroll
    for (int i = 0; i < 6; i++) v6[i] = (lane >= d) ? nv[i] : v6[i];
  }
  float ex[6];                                      // exclusive within wave
  #pragma unroll
  for (int i = 0; i < 6; i++) {
    float t = __shfl_up(v6[i], 1, 64);
    ex[i] = (lane > 0) ? t : 0.0f;
  }
  if (lane == 63) {
    #pragma unroll
    for (int i = 0; i < 6; i++) wtot[wib][i] = v6[i];
  }
  __syncthreads();

  // ---- wave 0: publish aggregate, decoupled lookback, publish inclusive ----
  if (wib == 0) {
    float g6[6];
    if (lane == 0) {
      #pragma unroll
      for (int i = 0; i < 6; i++) g6[i] = wtot[0][i];
      #pragma unroll
      for (int w = 1; w < 4; w++) {
        float ng[6];
        MV6(ng, sVm[6], g6, wtot[w]);               // B64 = W^64
        #pragma unroll
        for (int i = 0; i < 6; i++) g6[i] = ng[i];
      }
      #pragma unroll
      for (int i = 0; i < 6; i++)
        __hip_atomic_store(&AGp[(long)vbid*6+i], g6[i], __ATOMIC_RELAXED, AGENT);
      __hip_atomic_store(&flags[vbid], 1u, __ATOMIC_RELEASE, AGENT);
    }
    if (jb == 0) {
      if (lane == 0) {
        #pragma unroll
        for (int i = 0; i < 6; i++) {
          sO[i] = 0.0f;
          __hip_atomic_store(&INCp[(long)vbid*6+i], g6[i], __ATOMIC_RELAXED, AGENT);
        }
        __hip_atomic_store(&flags[vbid], 2u, __ATOMIC_RELEASE, AGENT);
      }
    } else {
      // parallel lookback: lane l watches predecessor at distance l+1; lane jb = virtual row start
      int l = lane;
      int pred = vbid - 1 - l;
      int l_inc;
      unsigned int fl;
      while (true) {
        fl = (l < jb) ? __hip_atomic_load(&flags[pred], __ATOMIC_ACQUIRE, AGENT) : 2u;
        unsigned long long b2 = __ballot(fl == 2u);
        l_inc = (int)(__ffsll((long long)b2) - 1);  // lowest lane with INC (<= jb always)
        unsigned long long b1 = __ballot(fl >= 1u);
        unsigned long long need = (l_inc >= 64) ? ~0ull : ((1ull << l_inc) - 1ull);
        if ((b1 & need) == need) break;
        __builtin_amdgcn_s_sleep(2);
      }
      if (l < l_inc) {
        #pragma unroll
        for (int i = 0; i < 6; i++)
          gstack[l][i] = __hip_atomic_load(&AGp[(long)pred*6+i], __ATOMIC_RELAXED, AGENT);
      } else if (l == l_inc && l < jb) {
        #pragma unroll
        for (int i = 0; i < 6; i++)
          gstack[l][i] = __hip_atomic_load(&INCp[(long)pred*6+i], __ATOMIC_RELAXED, AGENT);
      }
      if (lane == 0) {
        float v[6];
        if (l_inc == jb) {
          #pragma unroll
          for (int i = 0; i < 6; i++) v[i] = 0.0f;
        } else {
          #pragma unroll
          for (int i = 0; i < 6; i++) v[i] = gstack[l_inc][i];
        }
        for (int l2 = l_inc - 1; l2 >= 0; --l2) {   // replay forward with B256
          float nv[6];
          MV6(nv, sVm[8], v, gstack[l2]);
          #pragma unroll
          for (int i = 0; i < 6; i++) v[i] = nv[i];
        }
        #pragma unroll
        for (int i = 0; i < 6; i++) sO[i] = v[i];
        float inc[6];
        MV6(inc, sVm[8], v, g6);                    // INC = g + B256*O (canonical fma order)
        #pragma unroll
        for (int i = 0; i < 6; i++)
          __hip_atomic_store(&INCp[(long)vbid*6+i], inc[i], __ATOMIC_RELAXED, AGENT);
        __hip_atomic_store(&flags[vbid], 2u, __ATOMIC_RELEASE, AGENT);
      }
    }
  }
  __syncthreads();

  // ---- absolute entry: E = ex + W^lane * (wave-absolute offset) ----
  float wabs[6];
  #pragma unroll
  for (int i = 0; i < 6; i++) wabs[i] = sO[i];
  for (int w = 0; w < wib; w++) {
    float nv[6];
    MV6(nv, sVm[6], wabs, wtot[w]);
    #pragma unroll
    for (int i = 0; i < 6; i++) wabs[i] = nv[i];
  }
  float m[6];
  #pragma unroll
  for (int i = 0; i < 6; i++) m[i] = wabs[i];
  float z6[6] = {0,0,0,0,0,0};
  #pragma unroll
  for (int k = 0; k < 6; k++) {
    if ((lane >> k) & 1) {
      float nm[6];
      MV6(nm, sVm[k], m, z6);
      #pragma unroll
      for (int i = 0; i < 6; i++) m[i] = nm[i];
    }
  }

  // ---- emit from entry state over the still-resident LDS audio ----
  if (valid) {
    LOAD_COEFS(scoef);
    float s11=ex[0]+m[0], s21=ex[1]+m[1], s12=ex[2]+m[2],
          s22=ex[3]+m[3], s13=ex[4]+m[4], s23=ex[5]+m[5];
    int n4 = (ci == NCH - 1) ? 2 : 8;
    float* rowp = slab + (lane << 5);
    int xr = lane & 7;
    float y3;
    if (n4 == 8) {
      #pragma unroll
      for (int j4 = 0; j4 < 8; j4++) {
        float* p = rowp + ((j4 ^ xr) << 2);
        float4 v = *(const float4*)p;
        float4 o;
        CASCADE_STEP(v.x); o.x = y3;
        CASCADE_STEP(v.y); o.y = y3;
        CASCADE_STEP(v.z); o.z = y3;
        CASCADE_STEP(v.w); o.w = y3;
        *(float4*)p = o;
      }
    } else {
      for (int j4 = 0; j4 < 2; j4++) {
        float* p = rowp + ((j4 ^ xr) << 2);
        float4 v = *(const float4*)p;
        float4 o;
        CASCADE_STEP(v.x); o.x = y3;
        CASCADE_STEP(v.y); o.y = y3;
        CASCADE_STEP(v.z); o.z = y3;
        CASCADE_STEP(v.w); o.w = y3;
        *(float4*)p = o;
      }
    }
  }
  __syncthreads();
  float4* yp = (float4*)(y + rowbase + s0);
  if (span4 == 512) {
    #pragma unroll
    for (int i = 0; i < 8; i++) {
      int g = (i << 6) + lane;
      int s = (g & ~7) | ((g & 7) ^ ((g >> 3) & 7));
      yp[g] = *(const float4*)(slab + (s << 2));
    }
  } else {
    #pragma unroll
    for (int i = 0; i < 8; i++) {
      int g = (i << 6) + lane;
      int s = (g & ~7) | ((g & 7) ^ ((g >> 3) & 7));
      if (g < span4) yp[g] = *(const float4*)(slab + (s << 2));
    }
  }
}

extern "C" void kernel_launch(void* const* d_in, const int* in_sizes, int n_in,
                              void* d_out, int out_size, void* d_ws, size_t ws_size,
                              hipStream_t stream) {
  const float* audio = (const float*)d_in[0];
  const float* qs    = (const float*)d_in[1];
  const float* gains = (const float*)d_in[2];
  float* out = (float*)d_out;
  float* ws  = (float*)d_ws;

  // zero ticket + flags (7040 B); AG/INC are flag-guarded, no init needed
  hipMemsetAsync(d_ws, 0, 7040, stream);
  hipLaunchKernelGGL(fused, dim3(NBLK), dim3(256), 0, stream, audio, qs, gains, out, ws);
}

// Round 10
// 66.093 us; speedup vs baseline: 1.9958x; 1.9958x over previous
//
#include <hip/hip_runtime.h>
#include <math.h>

#define SR      44100.0
#define T_LEN   441000
#define B_ROWS  32
#define NCH     13782            // chunks per row (32 samples each; last = 8)
#define BPR     54               // blocks per row (256 chunks per block)
#define NBLK    (B_ROWS * BPR)   // 1728
#define NMAT    14               // W^(2^k), k=0..13  (W = A^32; B = W^256 = k=8)

// ws layout (floats)
#define WS_MAT  0                // NMAT*36 = 504
#define WS_AG   512              // NBLK*6 block aggregates

typedef __attribute__((address_space(1))) const void gconst_t;
typedef __attribute__((address_space(3))) void lds_t;
#define GL2LDS(gp, lp) __builtin_amdgcn_global_load_lds((gconst_t*)(gp), (lds_t*)(lp), 16, 0, 0)

// ---------------- shared helpers (verified rounds 3..9) ----------------

#define COMPUTE_COEFS(scoef, dco, qs, gains) do { \
    if (threadIdx.x < 3) { \
      int f = threadIdx.x; \
      double cfq = 100.0 * exp(log(30.0) * (double)f / 3.0); \
      double w0 = 2.0 * M_PI * cfq / SR; \
      double alpha = sin(w0) / (2.0 * (double)qs[f]); \
      double Ag = exp((double)gains[f] * (2.302585092994045684 / 40.0)); \
      double a0 = 1.0 + alpha / Ag; \
      double c0 = (1.0 + alpha * Ag) / a0; \
      double c1 = (-2.0 * cos(w0)) / a0; \
      double c2 = (1.0 - alpha * Ag) / a0; \
      double c3 = c1; \
      double c4 = (1.0 - alpha / Ag) / a0; \
      dco[f*5+0]=c0; dco[f*5+1]=c1; dco[f*5+2]=c2; dco[f*5+3]=c3; dco[f*5+4]=c4; \
      scoef[f*5+0]=(float)c0; scoef[f*5+1]=(float)c1; scoef[f*5+2]=(float)c2; \
      scoef[f*5+3]=(float)c3; scoef[f*5+4]=(float)c4; \
    } \
  } while (0)

#define LOAD_COEFS(cf) \
  const float b00=cf[0],b10=cf[1],b20=cf[2],a10=cf[3],a20=cf[4]; \
  const float b01=cf[5],b11=cf[6],b21=cf[7],a11=cf[8],a21=cf[9]; \
  const float b02=cf[10],b12=cf[11],b22=cf[12],a12=cf[13],a22=cf[14];

#define CASCADE_STEP(xx) do { \
    float y1 = fmaf(b00, (xx), s11); \
    s11 = fmaf(-a10, y1, fmaf(b10, (xx), s21)); \
    s21 = fmaf(-a20, y1, b20 * (xx)); \
    float y2 = fmaf(b01, y1, s12); \
    s12 = fmaf(-a11, y2, fmaf(b11, y1, s22)); \
    s22 = fmaf(-a21, y2, b21 * y1); \
    y3 = fmaf(b02, y2, s13); \
    s13 = fmaf(-a12, y3, fmaf(b12, y2, s23)); \
    s23 = fmaf(-a22, y3, b22 * y2); \
  } while (0)

#define MV6(dst, M, v, add) do { \
    _Pragma("unroll") \
    for (int _i = 0; _i < 6; _i++) { \
      float _s = (add)[_i]; \
      _Pragma("unroll") \
      for (int _k = 0; _k < 6; _k++) _s = fmaf((M)[_i*6+_k], (v)[_k], _s); \
      (dst)[_i] = _s; \
    } \
  } while (0)

__device__ __forceinline__ void mm6d(const double* X, const double* Y, double* Z, int t) {
  if (t < 36) {
    int i = t / 6, j = t % 6;
    double s = 0.0;
    #pragma unroll
    for (int k = 0; k < 6; k++) s += X[i*6+k] * Y[k*6+j];
    Z[t] = s;
  }
}

// Staging swizzle: LDS float4-slot s holds global float4 g(s)=(s&~7)|((s&7)^((s>>3)&7)).
// Involution, line-local (coalescing intact), ds_read_b128 bank-balanced.

#define STAGE_AUDIO() do { \
    if (span4 == 512) { \
      _Pragma("unroll") \
      for (int i = 0; i < 8; i++) { \
        int s = (i << 6) + lane; \
        int g = (s & ~7) | ((s & 7) ^ ((s >> 3) & 7)); \
        GL2LDS(xp + g, slab + (i << 8)); \
      } \
    } else { \
      _Pragma("unroll") \
      for (int i = 0; i < 8; i++) { \
        int s = (i << 6) + lane; \
        int g = (s & ~7) | ((s & 7) ^ ((s >> 3) & 7)); \
        if (g < span4) GL2LDS(xp + g, slab + (i << 8)); \
      } \
    } \
  } while (0)

// cascade own chunk (32 samples) from zero state -> f6
#define CHUNK_FINALS(f6) do { \
    if (valid) { \
      int n4 = (ci == NCH - 1) ? 2 : 8; \
      const float* rowp = slab + (lane << 5); \
      int xr = lane & 7; \
      float s11=0,s21=0,s12=0,s22=0,s13=0,s23=0, y3; \
      if (n4 == 8) { \
        _Pragma("unroll") \
        for (int j4 = 0; j4 < 8; j4++) { \
          float4 v = *(const float4*)(rowp + ((j4 ^ xr) << 2)); \
          CASCADE_STEP(v.x); CASCADE_STEP(v.y); CASCADE_STEP(v.z); CASCADE_STEP(v.w); \
        } \
      } else { \
        for (int j4 = 0; j4 < 2; j4++) { \
          float4 v = *(const float4*)(rowp + ((j4 ^ xr) << 2)); \
          CASCADE_STEP(v.x); CASCADE_STEP(v.y); CASCADE_STEP(v.z); CASCADE_STEP(v.w); \
        } \
      } \
      (void)y3; \
      f6[0]=s11; f6[1]=s21; f6[2]=s12; f6[3]=s22; f6[4]=s13; f6[5]=s23; \
    } \
  } while (0)

// in-wave inclusive shuffle scan over 64 chunk-maps (Wp(k) = W^(2^k) table base)
#define WAVE_SCAN(v6, f6, Wp) do { \
    _Pragma("unroll") \
    for (int i = 0; i < 6; i++) v6[i] = f6[i]; \
    _Pragma("unroll") \
    for (int k = 0; k < 6; k++) { \
      int d = 1 << k; \
      float u[6]; \
      _Pragma("unroll") \
      for (int i = 0; i < 6; i++) u[i] = __shfl_up(v6[i], d, 64); \
      float nv[6]; \
      MV6(nv, (Wp) + k*36, u, v6); \
      _Pragma("unroll") \
      for (int i = 0; i < 6; i++) v6[i] = (lane >= d) ? nv[i] : v6[i]; \
    } \
  } while (0)

// ---------------- kA: block aggregates only (no entry traffic) ----------------

__global__ __launch_bounds__(256) void kA_agg(const float* __restrict__ x,
                                              const float* __restrict__ qs,
                                              const float* __restrict__ gains,
                                              float* __restrict__ ws) {
  __shared__ __align__(16) float lds[4 * 2048];
  __shared__ double Da[36], Db[36], dco[15];
  __shared__ float sVm[NMAT][36];
  __shared__ float scoef[16];
  __shared__ float wtot[4][6];
  const int tid = threadIdx.x;
  const int wib = tid >> 6, lane = tid & 63;
  const int b = blockIdx.x;
  const int row = b / BPR, jb = b - row * BPR;
  const int wci = (jb << 2) + wib;
  long rowbase = (long)row * T_LEN;
  int s0 = wci << 11;
  int span4 = (min(2048, T_LEN - s0)) >> 2;
  const float4* xp = (const float4*)(x + rowbase + s0);
  float* slab = lds + (wib << 11);
  STAGE_AUDIO();
  COMPUTE_COEFS(scoef, dco, qs, gains);
  // wave 0: matrix chain in double (DS ops in-order within a wave; no block barriers)
  if (wib == 0) {
    if (lane == 0) {
      double u[7] = {0,0,0,0,0,0,1};
      for (int f = 0; f < 3; f++) {
        double c0=dco[f*5+0], c1=dco[f*5+1], c2=dco[f*5+2], c3=dco[f*5+3], c4=dco[f*5+4];
        double yv[7], s1p[7], s2p[7];
        for (int i = 0; i < 7; i++) {
          yv[i]  = c0 * u[i] + ((i == 2*f)   ? 1.0 : 0.0);
          s1p[i] = c1 * u[i] + ((i == 2*f+1) ? 1.0 : 0.0) - c3 * yv[i];
          s2p[i] = c2 * u[i] - c4 * yv[i];
        }
        for (int i = 0; i < 6; i++) { Da[(2*f)*6+i] = s1p[i]; Da[(2*f+1)*6+i] = s2p[i]; }
        for (int i = 0; i < 7; i++) u[i] = yv[i];
      }
    }
    double* cur = Da; double* oth = Db;
    #pragma unroll
    for (int s = 0; s < 5; s++) {                  // A -> A^32 = W
      mm6d(cur, cur, oth, lane);
      double* tm = cur; cur = oth; oth = tm;
    }
    #pragma unroll
    for (int k = 0; k < NMAT; k++) {               // sVm[k] = W^(2^k)
      if (lane < 36) {
        float wv = (float)cur[lane];
        sVm[k][lane] = wv;
        if (b == 0) ws[WS_MAT + k*36 + lane] = wv;
      }
      if (k < NMAT - 1) {
        mm6d(cur, cur, oth, lane);
        double* tm = cur; cur = oth; oth = tm;
      }
    }
  }
  __syncthreads();

  int ci = (jb << 8) + tid;
  bool valid = ci < NCH;
  float f6[6] = {0,0,0,0,0,0};
  LOAD_COEFS(scoef);
  CHUNK_FINALS(f6);
  float v6[6];
  WAVE_SCAN(v6, f6, &sVm[0][0]);
  if (lane == 63) {
    #pragma unroll
    for (int i = 0; i < 6; i++) wtot[wib][i] = v6[i];
  }
  __syncthreads();
  // block aggregate (only consumed for jb < 53)
  if (tid == 0 && jb < BPR - 1) {
    float g6[6];
    #pragma unroll
    for (int i = 0; i < 6; i++) g6[i] = wtot[0][i];
    #pragma unroll
    for (int w = 1; w < 4; w++) {
      float ng[6];
      MV6(ng, sVm[6], g6, wtot[w]);                // W^64
      #pragma unroll
      for (int i = 0; i < 6; i++) g6[i] = ng[i];
    }
    #pragma unroll
    for (int i = 0; i < 6; i++) ws[WS_AG + (long)b * 6 + i] = g6[i];
  }
}

// ---------------- kC: row-offset scan + recompute + emit ----------------

__global__ __launch_bounds__(256) void kC_emit(const float* __restrict__ x,
                                               const float* __restrict__ qs,
                                               const float* __restrict__ gains,
                                               float* __restrict__ y,
                                               const float* __restrict__ ws) {
  __shared__ __align__(16) float lds[4 * 2048];
  __shared__ float smat[NMAT * 36];
  __shared__ float scoef[16];
  __shared__ double dco[15];
  __shared__ float wtot[4][6];
  __shared__ float sO[6];
  const int tid = threadIdx.x;
  const int wib = tid >> 6, lane = tid & 63;
  const int b = blockIdx.x;
  const int row = b / BPR, jb = b - row * BPR;
  const int wci = (jb << 2) + wib;
  long rowbase = (long)row * T_LEN;
  int s0 = wci << 11;
  int span4 = (min(2048, T_LEN - s0)) >> 2;
  const float4* xp = (const float4*)(x + rowbase + s0);
  float* slab = lds + (wib << 11);
  STAGE_AUDIO();
  for (int i = tid; i < NMAT * 36; i += 256) smat[i] = ws[WS_MAT + i];
  // wave 0 lanes load this row's block aggregates into registers
  float ag[6] = {0,0,0,0,0,0};
  if (wib == 0 && lane < BPR - 1) {
    const float* p = ws + WS_AG + ((long)row * BPR + lane) * 6;
    #pragma unroll
    for (int i = 0; i < 6; i++) ag[i] = p[i];
  }
  COMPUTE_COEFS(scoef, dco, qs, gains);
  if (tid == 0 && jb == 0) {
    #pragma unroll
    for (int i = 0; i < 6; i++) sO[i] = 0.0f;
  }
  __syncthreads();

  // wave 0: exclusive row offset for this block = inclusive scan of AG[0..jb)
  if (wib == 0 && jb > 0) {
    float v6s[6];
    #pragma unroll
    for (int i = 0; i < 6; i++) v6s[i] = ag[i];
    #pragma unroll
    for (int k = 0; k < 6; k++) {
      int d = 1 << k;
      float u[6];
      #pragma unroll
      for (int i = 0; i < 6; i++) u[i] = __shfl_up(v6s[i], d, 64);
      float nv[6];
      MV6(nv, smat + (8 + k) * 36, u, v6s);        // B^(2^k), B = W^256
      #pragma unroll
      for (int i = 0; i < 6; i++) v6s[i] = (lane >= d) ? nv[i] : v6s[i];
    }
    if (lane == jb - 1) {
      #pragma unroll
      for (int i = 0; i < 6; i++) sO[i] = v6s[i];
    }
  }

  // recompute finals + in-wave scan (bit-identical to kA)
  int ci = (jb << 8) + tid;
  bool valid = ci < NCH;
  float f6[6] = {0,0,0,0,0,0};
  LOAD_COEFS(scoef);
  CHUNK_FINALS(f6);
  float v6[6];
  WAVE_SCAN(v6, f6, smat);
  float ex[6];
  #pragma unroll
  for (int i = 0; i < 6; i++) {
    float t = __shfl_up(v6[i], 1, 64);
    ex[i] = (lane > 0) ? t : 0.0f;
  }
  if (lane == 63) {
    #pragma unroll
    for (int i = 0; i < 6; i++) wtot[wib][i] = v6[i];
  }
  __syncthreads();

  // absolutize: entry = ex + W^lane * fold(sO; wtot[0..wib))
  float wabs[6];
  #pragma unroll
  for (int i = 0; i < 6; i++) wabs[i] = sO[i];
  for (int w = 0; w < wib; w++) {
    float nv[6];
    MV6(nv, smat + 6 * 36, wabs, wtot[w]);         // W^64
    #pragma unroll
    for (int i = 0; i < 6; i++) wabs[i] = nv[i];
  }
  float m[6];
  #pragma unroll
  for (int i = 0; i < 6; i++) m[i] = wabs[i];
  float z6[6] = {0,0,0,0,0,0};
  #pragma unroll
  for (int k = 0; k < 6; k++) {
    if ((lane >> k) & 1) {
      float nm[6];
      MV6(nm, smat + k * 36, m, z6);
      #pragma unroll
      for (int i = 0; i < 6; i++) m[i] = nm[i];
    }
  }

  // emit from entry state over still-resident LDS audio
  if (valid) {
    float s11=ex[0]+m[0], s21=ex[1]+m[1], s12=ex[2]+m[2],
          s22=ex[3]+m[3], s13=ex[4]+m[4], s23=ex[5]+m[5];
    int n4 = (ci == NCH - 1) ? 2 : 8;
    float* rowp = slab + (lane << 5);
    int xr = lane & 7;
    float y3;
    if (n4 == 8) {
      #pragma unroll
      for (int j4 = 0; j4 < 8; j4++) {
        float* p = rowp + ((j4 ^ xr) << 2);
        float4 v = *(const float4*)p;
        float4 o;
        CASCADE_STEP(v.x); o.x = y3;
        CASCADE_STEP(v.y); o.y = y3;
        CASCADE_STEP(v.z); o.z = y3;
        CASCADE_STEP(v.w); o.w = y3;
        *(float4*)p = o;
      }
    } else {
      for (int j4 = 0; j4 < 2; j4++) {
        float* p = rowp + ((j4 ^ xr) << 2);
        float4 v = *(const float4*)p;
        float4 o;
        CASCADE_STEP(v.x); o.x = y3;
        CASCADE_STEP(v.y); o.y = y3;
        CASCADE_STEP(v.z); o.z = y3;
        CASCADE_STEP(v.w); o.w = y3;
        *(float4*)p = o;
      }
    }
  }
  __syncthreads();
  float4* yp = (float4*)(y + rowbase + s0);
  if (span4 == 512) {
    #pragma unroll
    for (int i = 0; i < 8; i++) {
      int g = (i << 6) + lane;
      int s = (g & ~7) | ((g & 7) ^ ((g >> 3) & 7));
      yp[g] = *(const float4*)(slab + (s << 2));
    }
  } else {
    #pragma unroll
    for (int i = 0; i < 8; i++) {
      int g = (i << 6) + lane;
      int s = (g & ~7) | ((g & 7) ^ ((g >> 3) & 7));
      if (g < span4) yp[g] = *(const float4*)(slab + (s << 2));
    }
  }
}

extern "C" void kernel_launch(void* const* d_in, const int* in_sizes, int n_in,
                              void* d_out, int out_size, void* d_ws, size_t ws_size,
                              hipStream_t stream) {
  const float* audio = (const float*)d_in[0];
  const float* qs    = (const float*)d_in[1];
  const float* gains = (const float*)d_in[2];
  float* out = (float*)d_out;
  float* ws  = (float*)d_ws;

  hipLaunchKernelGGL(kA_agg, dim3(NBLK), dim3(256), 0, stream, audio, qs, gains, ws);
  hipLaunchKernelGGL(kC_emit, dim3(NBLK), dim3(256), 0, stream, audio, qs, gains, out, ws);
}

// Round 11
// 59.962 us; speedup vs baseline: 2.1999x; 1.1022x over previous
//
#include <hip/hip_runtime.h>
#include <math.h>

#define SR      44100.0
#define T_LEN   441000
#define B_ROWS  32
#define NCH     13782            // chunks per row (32 samples each; last = 8)
#define GCH     (B_ROWS * NCH)
#define BPR     54               // blocks per row (256 chunks per block)
#define NBLK    (B_ROWS * BPR)   // 1728
#define NMAT    14               // W^(2^k), k=0..13  (W = A^32; B = W^256 = k=8)

// ws layout (floats)
#define WS_MAT  0                // 14*36 = 504
#define WS_AG   512              // NBLK*6 block aggregates
#define WS_F    21248            // GCH*6: relative entries (written by kA)

typedef __attribute__((address_space(1))) const void gconst_t;
typedef __attribute__((address_space(3))) void lds_t;
#define GL2LDS(gp, lp) __builtin_amdgcn_global_load_lds((gconst_t*)(gp), (lds_t*)(lp), 16, 0, 0)

// ---------------- shared helpers (verified rounds 3..10) ----------------

#define COMPUTE_COEFS(scoef, dco, qs, gains) do { \
    if (threadIdx.x < 3) { \
      int f = threadIdx.x; \
      double cfq = 100.0 * exp(log(30.0) * (double)f / 3.0); \
      double w0 = 2.0 * M_PI * cfq / SR; \
      double alpha = sin(w0) / (2.0 * (double)qs[f]); \
      double Ag = exp((double)gains[f] * (2.302585092994045684 / 40.0)); \
      double a0 = 1.0 + alpha / Ag; \
      double c0 = (1.0 + alpha * Ag) / a0; \
      double c1 = (-2.0 * cos(w0)) / a0; \
      double c2 = (1.0 - alpha * Ag) / a0; \
      double c3 = c1; \
      double c4 = (1.0 - alpha / Ag) / a0; \
      dco[f*5+0]=c0; dco[f*5+1]=c1; dco[f*5+2]=c2; dco[f*5+3]=c3; dco[f*5+4]=c4; \
      scoef[f*5+0]=(float)c0; scoef[f*5+1]=(float)c1; scoef[f*5+2]=(float)c2; \
      scoef[f*5+3]=(float)c3; scoef[f*5+4]=(float)c4; \
    } \
  } while (0)

#define LOAD_COEFS(cf) \
  const float b00=cf[0],b10=cf[1],b20=cf[2],a10=cf[3],a20=cf[4]; \
  const float b01=cf[5],b11=cf[6],b21=cf[7],a11=cf[8],a21=cf[9]; \
  const float b02=cf[10],b12=cf[11],b22=cf[12],a12=cf[13],a22=cf[14];

#define CASCADE_STEP(xx) do { \
    float y1 = fmaf(b00, (xx), s11); \
    s11 = fmaf(-a10, y1, fmaf(b10, (xx), s21)); \
    s21 = fmaf(-a20, y1, b20 * (xx)); \
    float y2 = fmaf(b01, y1, s12); \
    s12 = fmaf(-a11, y2, fmaf(b11, y1, s22)); \
    s22 = fmaf(-a21, y2, b21 * y1); \
    y3 = fmaf(b02, y2, s13); \
    s13 = fmaf(-a12, y3, fmaf(b12, y2, s23)); \
    s23 = fmaf(-a22, y3, b22 * y2); \
  } while (0)

#define MV6(dst, M, v, add) do { \
    _Pragma("unroll") \
    for (int _i = 0; _i < 6; _i++) { \
      float _s = (add)[_i]; \
      _Pragma("unroll") \
      for (int _k = 0; _k < 6; _k++) _s = fmaf((M)[_i*6+_k], (v)[_k], _s); \
      (dst)[_i] = _s; \
    } \
  } while (0)

__device__ __forceinline__ void mm6d(const double* X, const double* Y, double* Z, int t) {
  if (t < 36) {
    int i = t / 6, j = t % 6;
    double s = 0.0;
    #pragma unroll
    for (int k = 0; k < 6; k++) s += X[i*6+k] * Y[k*6+j];
    Z[t] = s;
  }
}

// Staging swizzle: LDS float4-slot s holds global float4 g(s)=(s&~7)|((s&7)^((s>>3)&7)).
// Involution, line-local (coalescing intact), ds_read_b128 bank-balanced.

#define STAGE_AUDIO() do { \
    if (span4 == 512) { \
      _Pragma("unroll") \
      for (int i = 0; i < 8; i++) { \
        int s = (i << 6) + lane; \
        int g = (s & ~7) | ((s & 7) ^ ((s >> 3) & 7)); \
        GL2LDS(xp + g, slab + (i << 8)); \
      } \
    } else { \
      _Pragma("unroll") \
      for (int i = 0; i < 8; i++) { \
        int s = (i << 6) + lane; \
        int g = (s & ~7) | ((s & 7) ^ ((s >> 3) & 7)); \
        if (g < span4) GL2LDS(xp + g, slab + (i << 8)); \
      } \
    } \
  } while (0)

// ---------------- kA: finals + in-block LDS scan -> relative entries + aggregates ----------------

__global__ __launch_bounds__(256) void kA_scan(const float* __restrict__ x,
                                               const float* __restrict__ qs,
                                               const float* __restrict__ gains,
                                               float* __restrict__ ws) {
  __shared__ __align__(16) float lds[4 * 2048];   // audio slabs; later scan ping-pong bufs
  __shared__ double Da[36], Db[36];
  __shared__ double dco[15];
  __shared__ float sVm[NMAT][36];
  __shared__ float scoef[16];
  const int tid = threadIdx.x;
  const int wib = tid >> 6, lane = tid & 63;
  const int b = blockIdx.x;
  const int row = b / BPR, jb = b - row * BPR;
  const int wci = (jb << 2) + wib;
  long rowbase = (long)row * T_LEN;
  int s0 = wci << 11;
  int span4 = (min(2048, T_LEN - s0)) >> 2;        // 512, or 170 for last wave of row
  const float4* xp = (const float4*)(x + rowbase + s0);
  float* slab = lds + (wib << 11);
  STAGE_AUDIO();
  COMPUTE_COEFS(scoef, dco, qs, gains);
  // wave 0 only: matrix chain (DS ops in-order within a wave; no block barriers)
  if (wib == 0) {
    if (lane == 0) {
      double u[7] = {0,0,0,0,0,0,1};   // current filter input as linear form over (S, x)
      for (int f = 0; f < 3; f++) {
        double c0=dco[f*5+0], c1=dco[f*5+1], c2=dco[f*5+2], c3=dco[f*5+3], c4=dco[f*5+4];
        double yv[7], s1p[7], s2p[7];
        for (int i = 0; i < 7; i++) {
          yv[i]  = c0 * u[i] + ((i == 2*f)   ? 1.0 : 0.0);
          s1p[i] = c1 * u[i] + ((i == 2*f+1) ? 1.0 : 0.0) - c3 * yv[i];
          s2p[i] = c2 * u[i] - c4 * yv[i];
        }
        for (int i = 0; i < 6; i++) { Da[(2*f)*6+i] = s1p[i]; Da[(2*f+1)*6+i] = s2p[i]; }
        for (int i = 0; i < 7; i++) u[i] = yv[i];
      }
    }
    double* cur = Da; double* oth = Db;
    #pragma unroll
    for (int s = 0; s < 5; s++) {                  // A -> A^32 = W
      mm6d(cur, cur, oth, lane);
      double* tm = cur; cur = oth; oth = tm;
    }
    #pragma unroll
    for (int k = 0; k < NMAT; k++) {               // publish W^(2^k)
      if (lane < 36) {
        float wv = (float)cur[lane];
        sVm[k][lane] = wv;
        if (b == 0) ws[WS_MAT + k*36 + lane] = wv;
      }
      if (k < NMAT - 1) {
        mm6d(cur, cur, oth, lane);
        double* tm = cur; cur = oth; oth = tm;
      }
    }
  }
  __syncthreads();

  // cascade over own chunk (32 samples) from zero state
  int ci = (jb << 8) + tid;                        // chunk index within row
  bool valid = ci < NCH;
  float f6[6] = {0,0,0,0,0,0};
  if (valid) {
    LOAD_COEFS(scoef);
    int n4 = (ci == NCH - 1) ? 2 : 8;
    const float* rowp = slab + (lane << 5);
    int xr = lane & 7;
    float s11=0,s21=0,s12=0,s22=0,s13=0,s23=0, y3;
    if (n4 == 8) {
      #pragma unroll
      for (int j4 = 0; j4 < 8; j4++) {
        float4 v = *(const float4*)(rowp + ((j4 ^ xr) << 2));
        CASCADE_STEP(v.x); CASCADE_STEP(v.y); CASCADE_STEP(v.z); CASCADE_STEP(v.w);
      }
    } else {
      for (int j4 = 0; j4 < 2; j4++) {
        float4 v = *(const float4*)(rowp + ((j4 ^ xr) << 2));
        CASCADE_STEP(v.x); CASCADE_STEP(v.y); CASCADE_STEP(v.z); CASCADE_STEP(v.w);
      }
    }
    (void)y3;
    f6[0]=s11; f6[1]=s21; f6[2]=s12; f6[3]=s22; f6[4]=s13; f6[5]=s23;
  }
  __syncthreads();                                 // slab reads complete; reuse as scan bufs

  // in-block Hillis-Steele over 256 chunks (items: x -> W x + f)
  float* src = lds;          // 256*7 floats
  float* dst = lds + 1792;   // 256*7 floats
  #pragma unroll
  for (int i = 0; i < 6; i++) src[tid*7 + i] = f6[i];
  __syncthreads();
  for (int k = 0; k < 8; k++) {
    int d = 1 << k;
    float nv[6];
    if (tid >= d) { MV6(nv, sVm[k], src + (tid-d)*7, src + tid*7); }
    else {
      #pragma unroll
      for (int i = 0; i < 6; i++) nv[i] = src[tid*7 + i];
    }
    #pragma unroll
    for (int i = 0; i < 6; i++) dst[tid*7 + i] = nv[i];
    __syncthreads();
    float* tm = src; src = dst; dst = tm;
  }
  // relative entry = exclusive prefix; write once (no finals to memory)
  if (valid) {
    float e[6];
    if (tid > 0) {
      #pragma unroll
      for (int i = 0; i < 6; i++) e[i] = src[(tid-1)*7 + i];
    } else {
      #pragma unroll
      for (int i = 0; i < 6; i++) e[i] = 0.0f;
    }
    float2* E = (float2*)(ws + WS_F + ((long)row * NCH + ci) * 6);
    E[0] = make_float2(e[0], e[1]); E[1] = make_float2(e[2], e[3]); E[2] = make_float2(e[4], e[5]);
  }
  // block aggregate (inclusive of all 256 chunks) — only consumed for jb < 53
  if (tid == 255 && jb < BPR - 1) {
    #pragma unroll
    for (int i = 0; i < 6; i++) ws[WS_AG + ((long)row * BPR + jb) * 6 + i] = src[255*7 + i];
  }
}

// ---------------- kC: wave0 row-offset scan + absolutize + emit ----------------

__global__ __launch_bounds__(256) void kC_emit(const float* __restrict__ x,
                                               const float* __restrict__ qs,
                                               const float* __restrict__ gains,
                                               float* __restrict__ y,
                                               const float* __restrict__ ws) {
  __shared__ __align__(16) float lds[4 * 2048];
  __shared__ float smat[NMAT * 36];
  __shared__ float scoef[16];
  __shared__ double dco[15];
  __shared__ float sO[6];
  const int tid = threadIdx.x;
  const int wib = tid >> 6, lane = tid & 63;
  const int b = blockIdx.x;
  const int row = b / BPR, jb = b - row * BPR;
  const int wci = (jb << 2) + wib;
  long rowbase = (long)row * T_LEN;
  int s0 = wci << 11;
  int span4 = (min(2048, T_LEN - s0)) >> 2;
  const float4* xp = (const float4*)(x + rowbase + s0);
  float* slab = lds + (wib << 11);
  STAGE_AUDIO();
  // overlap under staging: matrices, aggregates (wave0 regs), coefs, relative entries
  for (int i = tid; i < NMAT * 36; i += 256) smat[i] = ws[WS_MAT + i];
  float ag[6] = {0,0,0,0,0,0};
  if (wib == 0 && lane < BPR - 1) {
    const float* p = ws + WS_AG + ((long)row * BPR + lane) * 6;
    #pragma unroll
    for (int i = 0; i < 6; i++) ag[i] = p[i];
  }
  COMPUTE_COEFS(scoef, dco, qs, gains);
  if (tid == 0 && jb == 0) {
    #pragma unroll
    for (int i = 0; i < 6; i++) sO[i] = 0.0f;
  }
  int ci = (jb << 8) + tid;
  bool valid = ci < NCH;
  float e0=0,e1v=0,e2=0,e3=0,e4=0,e5=0;
  if (valid) {
    const float2* E = (const float2*)(ws + WS_F + ((long)row * NCH + ci) * 6);
    float2 p0 = E[0], p1 = E[1], p2 = E[2];
    e0=p0.x; e1v=p0.y; e2=p1.x; e3=p1.y; e4=p2.x; e5=p2.y;
  }
  __syncthreads();                                 // smat + audio resident

  // wave 0: exclusive row offset O = inclusive B-scan of AG[0..jb)  (B = W^256)
  if (wib == 0 && jb > 0) {
    float v6s[6];
    #pragma unroll
    for (int i = 0; i < 6; i++) v6s[i] = ag[i];
    #pragma unroll
    for (int k = 0; k < 6; k++) {
      int d = 1 << k;
      float u[6];
      #pragma unroll
      for (int i = 0; i < 6; i++) u[i] = __shfl_up(v6s[i], d, 64);
      float nv[6];
      MV6(nv, smat + (8 + k) * 36, u, v6s);        // B^(2^k)
      #pragma unroll
      for (int i = 0; i < 6; i++) v6s[i] = (lane >= d) ? nv[i] : v6s[i];
    }
    if (lane == jb - 1) {
      #pragma unroll
      for (int i = 0; i < 6; i++) sO[i] = v6s[i];
    }
  }
  __syncthreads();                                 // sO ready

  if (valid) {
    LOAD_COEFS(scoef);
    // absolute entry = rel_entry + W^tid * O_block
    float m[6];
    #pragma unroll
    for (int i = 0; i < 6; i++) m[i] = sO[i];
    float z6[6] = {0,0,0,0,0,0};
    #pragma unroll
    for (int k = 0; k < 8; k++) {
      if ((tid >> k) & 1) {
        float nm[6];
        MV6(nm, smat + k*36, m, z6);
        #pragma unroll
        for (int i = 0; i < 6; i++) m[i] = nm[i];
      }
    }
    float s11=e0+m[0], s21=e1v+m[1], s12=e2+m[2], s22=e3+m[3], s13=e4+m[4], s23=e5+m[5];
    int n4 = (ci == NCH - 1) ? 2 : 8;
    float* rowp = slab + (lane << 5);
    int xr = lane & 7;
    float y3;
    if (n4 == 8) {
      #pragma unroll
      for (int j4 = 0; j4 < 8; j4++) {
        float* p = rowp + ((j4 ^ xr) << 2);
        float4 v = *(const float4*)p;
        float4 o;
        CASCADE_STEP(v.x); o.x = y3;
        CASCADE_STEP(v.y); o.y = y3;
        CASCADE_STEP(v.z); o.z = y3;
        CASCADE_STEP(v.w); o.w = y3;
        *(float4*)p = o;
      }
    } else {
      for (int j4 = 0; j4 < 2; j4++) {
        float* p = rowp + ((j4 ^ xr) << 2);
        float4 v = *(const float4*)p;
        float4 o;
        CASCADE_STEP(v.x); o.x = y3;
        CASCADE_STEP(v.y); o.y = y3;
        CASCADE_STEP(v.z); o.z = y3;
        CASCADE_STEP(v.w); o.w = y3;
        *(float4*)p = o;
      }
    }
  }
  __syncthreads();
  float4* yp = (float4*)(y + rowbase + s0);
  if (span4 == 512) {
    #pragma unroll
    for (int i = 0; i < 8; i++) {
      int g = (i << 6) + lane;
      int s = (g & ~7) | ((g & 7) ^ ((g >> 3) & 7));
      yp[g] = *(const float4*)(slab + (s << 2));
    }
  } else {
    #pragma unroll
    for (int i = 0; i < 8; i++) {
      int g = (i << 6) + lane;
      int s = (g & ~7) | ((g & 7) ^ ((g >> 3) & 7));
      if (g < span4) yp[g] = *(const float4*)(slab + (s << 2));
    }
  }
}

extern "C" void kernel_launch(void* const* d_in, const int* in_sizes, int n_in,
                              void* d_out, int out_size, void* d_ws, size_t ws_size,
                              hipStream_t stream) {
  const float* audio = (const float*)d_in[0];
  const float* qs    = (const float*)d_in[1];
  const float* gains = (const float*)d_in[2];
  float* out = (float*)d_out;
  float* ws  = (float*)d_ws;

  hipLaunchKernelGGL(kA_scan, dim3(NBLK), dim3(256), 0, stream, audio, qs, gains, ws);
  hipLaunchKernelGGL(kC_emit, dim3(NBLK), dim3(256), 0, stream, audio, qs, gains, out, ws);
}